// Round 11
// baseline (98.561 us; speedup 1.0000x reference)
//
#include <hip/hip_runtime.h>
#include <hip/hip_bf16.h>
#include <cstdint>

typedef __bf16 bf16x8 __attribute__((ext_vector_type(8)));
typedef float f32x16 __attribute__((ext_vector_type(16)));

#define BROWS 4096
#define DH    1024
#define KDIM  2048   // D_IN + D_H
#define NT    32     // K-tiles of 64

// ---------------- fused prep: concat(x,h)->bf16 xh  +  W transpose/interleave->wt ----------------
// Interleave grain 32 for 32x32 MFMA n-tiles: n' = (j>>5)*128 + g*32 + (j&31)
__global__ __launch_bounds__(256) void k_prep(const float* __restrict__ x,
                                              const float* __restrict__ h,
                                              const float* __restrict__ Wf,
                                              const float* __restrict__ Wi,
                                              const float* __restrict__ Wc,
                                              const float* __restrict__ Wo,
                                              __hip_bfloat16* __restrict__ xh,
                                              __hip_bfloat16* __restrict__ wt) {
  __shared__ float t[64][65];
  const int tid = threadIdx.x;
  if (blockIdx.x < 4096) {
    // concat(x,h) -> bf16 xh[4096][2048], 8 elems/thread
    int64_t idx = ((int64_t)blockIdx.x * 256 + tid) * 8;
    int row = (int)(idx >> 11);
    int col = (int)(idx & 2047);
    const float* src = (col < 1024) ? (x + (int64_t)row * 1024 + col)
                                    : (h + (int64_t)row * 1024 + (col - 1024));
    float4 v0 = reinterpret_cast<const float4*>(src)[0];
    float4 v1 = reinterpret_cast<const float4*>(src)[1];
    alignas(16) __hip_bfloat16 o8[8];
    o8[0] = __float2bfloat16(v0.x); o8[1] = __float2bfloat16(v0.y);
    o8[2] = __float2bfloat16(v0.z); o8[3] = __float2bfloat16(v0.w);
    o8[4] = __float2bfloat16(v1.x); o8[5] = __float2bfloat16(v1.y);
    o8[6] = __float2bfloat16(v1.z); o8[7] = __float2bfloat16(v1.w);
    *reinterpret_cast<int4*>(xh + idx) = *reinterpret_cast<const int4*>(o8);
  } else {
    // W_g[k][j] fp32 -> wt[n'][k] bf16, n' = (j>>5)*128 + g*32 + (j&31)
    const int b = blockIdx.x - 4096;   // 2048 = 4 gates * 16 jt * 32 kt
    const int g  = b & 3;
    const int jt = (b >> 2) & 15;
    const int kt = b >> 6;
    const float* W = (g == 0) ? Wf : (g == 1) ? Wi : (g == 2) ? Wc : Wo;
    const int j0 = jt << 6, k0 = kt << 6;
#pragma unroll
    for (int i = 0; i < 4; ++i) {
      int r = (tid >> 4) + (i << 4);
      int c = (tid & 15) << 2;
      float4 v = *reinterpret_cast<const float4*>(W + (int64_t)(k0 + r) * 1024 + j0 + c);
      t[r][c + 0] = v.x; t[r][c + 1] = v.y; t[r][c + 2] = v.z; t[r][c + 3] = v.w;
    }
    __syncthreads();
#pragma unroll
    for (int i = 0; i < 2; ++i) {
      int task = tid + (i << 8);
      int rr = task >> 3;            // local j index 0..63
      int kc = (task & 7) << 3;      // k-chunk 0,8,...,56
      int np = ((jt * 2 + (rr >> 5)) << 7) + (g << 5) + (rr & 31);
      alignas(16) __hip_bfloat16 o8[8];
#pragma unroll
      for (int e = 0; e < 8; ++e) o8[e] = __float2bfloat16(t[kc + e][rr]);
      *reinterpret_cast<int4*>(wt + (int64_t)np * KDIM + k0 + kc) =
          *reinterpret_cast<const int4*>(o8);
    }
  }
}

// ---------------- fused GEMM + LSTM epilogue: 256x256, 32x32x16 MFMA ----------------
__device__ __forceinline__ float sig_(float v) {
  return __builtin_amdgcn_rcpf(1.0f + __expf(-v));
}
__device__ __forceinline__ float tanh_(float v) {
  return fmaf(2.0f, __builtin_amdgcn_rcpf(1.0f + __expf(-2.0f * v)), -1.0f);
}

// LDS regions (elements): parity p, k-half kh:  A(p,kh) = p*32768 + kh*8192 (256 rows x 32)
//                                               B(p,kh) = p*32768 + 16384 + kh*8192
// Swizzle: phys 16B-chunk = logical ^ ((row>>1)&3); stage pre-swizzles the global source,
// gload_lds dest linear; reads XOR the chunk. global_load_lds imm offset = 0 always.
#define GLD(PTR, LOFF)                                                           \
  __builtin_amdgcn_global_load_lds(                                              \
      (const __attribute__((address_space(1))) void*)(PTR),                      \
      (__attribute__((address_space(3))) void*)(lds + (LOFF) + wslot), 16, 0, 0)

// stage A(parity,KH) and B(parity,KH): 4 loads (each covers 128 rows x 32 cols)
#define STG2(LP, KH_, PA, PB)                                                    \
  do {                                                                           \
    GLD((PA), (LP) + (KH_) * 8192);                                              \
    GLD((PA) + 128 * KDIM, (LP) + (KH_) * 8192 + 4096);                          \
    GLD((PB), (LP) + 16384 + (KH_) * 8192);                                      \
    GLD((PB) + 128 * KDIM, (LP) + 16384 + (KH_) * 8192 + 4096);                  \
  } while (0)

#define VM4 asm volatile("s_waitcnt vmcnt(4)" ::: "memory")
#define SB0 __builtin_amdgcn_sched_barrier(0)

// A fragments: av[mt*2+ks2] = A rows [wm*64+mt*32 .. +32), k = kh*32 + ks2*16 + hi*8
#define RD_AV(P, KH)                                                             \
  do {                                                                           \
    const __hip_bfloat16* _b = lds + (P) * 32768 + (KH) * 8192 + arow;           \
    av[0] = *reinterpret_cast<const bf16x8*>(_b + c0);                           \
    av[1] = *reinterpret_cast<const bf16x8*>(_b + c1);                           \
    av[2] = *reinterpret_cast<const bf16x8*>(_b + 1024 + c0);                    \
    av[3] = *reinterpret_cast<const bf16x8*>(_b + 1024 + c1);                    \
  } while (0)

// B fragments: bv[nt2*2+ks2] = B(n'-rows) [wn*128 + (2*NH+nt2)*32 .. +32)
#define RD_BV(P, KH, NH)                                                         \
  do {                                                                           \
    const __hip_bfloat16* _b = lds + (P) * 32768 + (KH) * 8192 + brow + (NH) * 2048; \
    bv[0] = *reinterpret_cast<const bf16x8*>(_b + c0);                           \
    bv[1] = *reinterpret_cast<const bf16x8*>(_b + c1);                           \
    bv[2] = *reinterpret_cast<const bf16x8*>(_b + 1024 + c0);                    \
    bv[3] = *reinterpret_cast<const bf16x8*>(_b + 1024 + c1);                    \
  } while (0)

#define MFMA32(A_, B_, C_) __builtin_amdgcn_mfma_f32_32x32x16_bf16(A_, B_, C_, 0, 0, 0)

// 8 MFMAs for (kh, NH): acc[mt][2NH+nt2] over ks2=0,1
#define MM8(NH)                                                                  \
  do {                                                                           \
    __builtin_amdgcn_s_barrier();                                                \
    __builtin_amdgcn_s_setprio(1);                                               \
    acc[0][2 * (NH)]     = MFMA32(av[0], bv[0], acc[0][2 * (NH)]);               \
    acc[0][2 * (NH) + 1] = MFMA32(av[0], bv[2], acc[0][2 * (NH) + 1]);           \
    acc[1][2 * (NH)]     = MFMA32(av[2], bv[0], acc[1][2 * (NH)]);               \
    acc[1][2 * (NH) + 1] = MFMA32(av[2], bv[2], acc[1][2 * (NH) + 1]);           \
    acc[0][2 * (NH)]     = MFMA32(av[1], bv[1], acc[0][2 * (NH)]);               \
    acc[0][2 * (NH) + 1] = MFMA32(av[1], bv[3], acc[0][2 * (NH) + 1]);           \
    acc[1][2 * (NH)]     = MFMA32(av[3], bv[1], acc[1][2 * (NH)]);               \
    acc[1][2 * (NH) + 1] = MFMA32(av[3], bv[3], acc[1][2 * (NH) + 1]);           \
    __builtin_amdgcn_s_setprio(0);                                               \
    __builtin_amdgcn_s_barrier();                                                \
  } while (0)

#define ADV do { a0 += 64; b0 += 64; } while (0)

__global__ __launch_bounds__(512, 2) void k_lstm_gemm(
    const __hip_bfloat16* __restrict__ xh, const __hip_bfloat16* __restrict__ wt,
    const float* __restrict__ cin,
    const float* __restrict__ bfp, const float* __restrict__ bip,
    const float* __restrict__ bcp, const float* __restrict__ bop,
    float* __restrict__ out) {
  __shared__ __hip_bfloat16 lds[65536];   // 128 KiB
  const int tid  = threadIdx.x;
  const int lane = tid & 63;
  const int wid  = tid >> 6;
  const int wm = wid >> 1, wn = wid & 1;   // 4 x 2 waves; wave output = 64 rows x 128 n-cols

  // T1: XCD-chunked bijective swizzle (256 blocks = 8 XCD x 32)
  const int bid  = blockIdx.x;
  const int flat = ((bid & 7) << 5) | (bid >> 3);
  const int m0 = (flat & 15) << 8;
  const int n0 = (flat >> 4) << 8;         // interleaved-gate column space

  f32x16 acc[2][4] = {};                   // [m-tile][gate]

  // ---- staging addressing (unchanged from proven kernel) ----
  const int wslot = wid << 9;
  const int cl = (((lane & 3) ^ ((lane >> 3) & 3)) << 3);
  const __hip_bfloat16* a0 = xh + (int64_t)(m0 + (tid >> 2)) * KDIM + cl;
  const __hip_bfloat16* b0 = wt + (int64_t)(n0 + (tid >> 2)) * KDIM + cl;

  // ---- fragment read bases (lane-constant) ----
  const int r5  = lane & 31;
  const int hi  = lane >> 5;
  const int lsw = (r5 >> 1) & 3;                 // swizzle XOR (row bases all ≡0 mod 8)
  const int c0  = (hi ^ lsw) << 3;               // ks2=0 chunk (elems)
  const int c1  = ((2 + hi) ^ lsw) << 3;         // ks2=1 chunk
  const int arow = (wm * 64 + r5) << 5;          // A region row offset
  const int brow = 16384 + ((wn * 128 + r5) << 5);

  bf16x8 av[4], bv[4];

  // ---- prologue: stage tile0 (parity 0); land kh0 ----
  STG2(0, 0, a0, b0);
  STG2(0, 1, a0 + 32, b0 + 32);
  ADV;
  VM4;
  __builtin_amdgcn_s_barrier();

  for (int t = 0; t < NT; t += 2) {
    {  // tile t (parity 0): stage tile t+1 -> parity 1
      RD_AV(0, 0); RD_BV(0, 0, 0); SB0;
      STG2(32768, 0, a0, b0);
      VM4; MM8(0);
      RD_BV(0, 0, 1); SB0;
      STG2(32768, 1, a0 + 32, b0 + 32);
      MM8(1);
      RD_AV(0, 1); RD_BV(0, 1, 0); SB0;
      VM4; MM8(0);
      RD_BV(0, 1, 1); SB0;
      MM8(1);
    }
    if (t != 30) ADV;
    {  // tile t+1 (parity 1): stage tile t+2 -> parity 0 (t=30: dead re-stage, in-bounds)
      RD_AV(1, 0); RD_BV(1, 0, 0); SB0;
      STG2(0, 0, a0, b0);
      VM4; MM8(0);
      RD_BV(1, 0, 1); SB0;
      STG2(0, 1, a0 + 32, b0 + 32);
      MM8(1);
      RD_AV(1, 1); RD_BV(1, 1, 0); SB0;
      VM4; MM8(0);
      RD_BV(1, 1, 1); SB0;
      MM8(1);
    }
    ADV;
  }

  // ---- fused LSTM epilogue (fp32 outputs: h_new, h_new, c_new) ----
  // 32x32 C/D: col = lane&31, row = (reg&3) + 8*(reg>>2) + 4*hi  [m74/m101]
  const int j = (((n0 >> 7) + wn) << 5) + r5;     // h-column in [0,1024)
  const float vbf = bfp[j], vbi = bip[j], vbc = bcp[j], vbo = bop[j];
  const int mb0 = m0 + wm * 64 + (hi << 2);
  float* outh1 = out;
  float* outh2 = out + (int64_t)BROWS * DH;
  float* outc  = out + (int64_t)2 * BROWS * DH;
#pragma unroll
  for (int mt = 0; mt < 2; ++mt) {
#pragma unroll
    for (int reg = 0; reg < 16; ++reg) {
      const int m = mb0 + mt * 32 + (reg & 3) + ((reg >> 2) << 3);
      const int64_t idx = (int64_t)m * DH + j;
      float fg = sig_(acc[mt][0][reg] + vbf);
      float ig = sig_(acc[mt][1][reg] + vbi);
      float cg = tanh_(acc[mt][2][reg] + vbc);
      float og = sig_(acc[mt][3][reg] + vbo);
      float cn = fg * cin[idx] + ig * cg;
      float hn = og * tanh_(cn);
      outh1[idx] = hn;
      outh2[idx] = hn;
      outc[idx]  = cn;
    }
  }
}

extern "C" void kernel_launch(void* const* d_in, const int* in_sizes, int n_in,
                              void* d_out, int out_size, void* d_ws, size_t ws_size,
                              hipStream_t stream) {
  const float* x  = (const float*)d_in[0];
  const float* h  = (const float*)d_in[1];
  const float* c  = (const float*)d_in[2];
  const float* Wf = (const float*)d_in[3];
  const float* bf = (const float*)d_in[4];
  const float* Wi = (const float*)d_in[5];
  const float* bi = (const float*)d_in[6];
  const float* Wc = (const float*)d_in[7];
  const float* bc = (const float*)d_in[8];
  const float* Wo = (const float*)d_in[9];
  const float* bo = (const float*)d_in[10];
  float* out = (float*)d_out;

  __hip_bfloat16* xh = (__hip_bfloat16*)d_ws;                    // 4096x2048 bf16 (16 MiB)
  __hip_bfloat16* wt = xh + (int64_t)BROWS * KDIM;               // 4096x2048 bf16 (16 MiB)

  hipLaunchKernelGGL(k_prep, dim3(6144), dim3(256), 0, stream,
                     x, h, Wf, Wi, Wc, Wo, xh, wt);
  hipLaunchKernelGGL(k_lstm_gemm, dim3(256), dim3(512), 0, stream,
                     xh, wt, c, bf, bi, bc, bo, out);
}

// Round 12
// 87.772 us; speedup vs baseline: 1.1229x; 1.1229x over previous
//
#include <hip/hip_runtime.h>
#include <hip/hip_bf16.h>
#include <cstdint>

typedef __bf16 bf16x8 __attribute__((ext_vector_type(8)));
typedef float f32x4 __attribute__((ext_vector_type(4)));

#define BROWS 4096
#define DH    1024
#define KDIM  2048   // D_IN + D_H
#define NT    32     // K-tiles of 64

// ---------------- fused prep: concat(x,h)->bf16 xh  +  W transpose/interleave->wt ----------------
__global__ __launch_bounds__(256) void k_prep(const float* __restrict__ x,
                                              const float* __restrict__ h,
                                              const float* __restrict__ Wf,
                                              const float* __restrict__ Wi,
                                              const float* __restrict__ Wc,
                                              const float* __restrict__ Wo,
                                              __hip_bfloat16* __restrict__ xh,
                                              __hip_bfloat16* __restrict__ wt) {
  __shared__ float t[64][65];
  const int tid = threadIdx.x;
  if (blockIdx.x < 4096) {
    // concat(x,h) -> bf16 xh[4096][2048], 8 elems/thread
    int64_t idx = ((int64_t)blockIdx.x * 256 + tid) * 8;
    int row = (int)(idx >> 11);
    int col = (int)(idx & 2047);
    const float* src = (col < 1024) ? (x + (int64_t)row * 1024 + col)
                                    : (h + (int64_t)row * 1024 + (col - 1024));
    float4 v0 = reinterpret_cast<const float4*>(src)[0];
    float4 v1 = reinterpret_cast<const float4*>(src)[1];
    alignas(16) __hip_bfloat16 o8[8];
    o8[0] = __float2bfloat16(v0.x); o8[1] = __float2bfloat16(v0.y);
    o8[2] = __float2bfloat16(v0.z); o8[3] = __float2bfloat16(v0.w);
    o8[4] = __float2bfloat16(v1.x); o8[5] = __float2bfloat16(v1.y);
    o8[6] = __float2bfloat16(v1.z); o8[7] = __float2bfloat16(v1.w);
    *reinterpret_cast<int4*>(xh + idx) = *reinterpret_cast<const int4*>(o8);
  } else {
    // W_g[k][j] fp32 -> wt[n'][k] bf16, n' = (j>>4)*64 + g*16 + (j&15)
    const int b = blockIdx.x - 4096;   // 2048 = 4 gates * 16 jt * 32 kt
    const int g  = b & 3;
    const int jt = (b >> 2) & 15;
    const int kt = b >> 6;
    const float* W = (g == 0) ? Wf : (g == 1) ? Wi : (g == 2) ? Wc : Wo;
    const int j0 = jt << 6, k0 = kt << 6;
#pragma unroll
    for (int i = 0; i < 4; ++i) {
      int r = (tid >> 4) + (i << 4);
      int c = (tid & 15) << 2;
      float4 v = *reinterpret_cast<const float4*>(W + (int64_t)(k0 + r) * 1024 + j0 + c);
      t[r][c + 0] = v.x; t[r][c + 1] = v.y; t[r][c + 2] = v.z; t[r][c + 3] = v.w;
    }
    __syncthreads();
#pragma unroll
    for (int i = 0; i < 2; ++i) {
      int task = tid + (i << 8);
      int rr = task >> 3;
      int kc = (task & 7) << 3;
      int np = (((jt << 2) + (rr >> 4)) << 6) + (g << 4) + (rr & 15);
      alignas(16) __hip_bfloat16 o8[8];
#pragma unroll
      for (int e = 0; e < 8; ++e) o8[e] = __float2bfloat16(t[kc + e][rr]);
      *reinterpret_cast<int4*>(wt + (int64_t)np * KDIM + k0 + kc) =
          *reinterpret_cast<const int4*>(o8);
    }
  }
}

// ---------------- fused GEMM + LSTM epilogue: 256x256, asm ds_read + counted lgkmcnt ----------------
__device__ __forceinline__ float sig_(float v) {
  return __builtin_amdgcn_rcpf(1.0f + __expf(-v));
}
__device__ __forceinline__ float tanh_(float v) {
  return fmaf(2.0f, __builtin_amdgcn_rcpf(1.0f + __expf(-2.0f * v)), -1.0f);
}

// LDS regions (bytes): parity p, k-half kh:  A(p,kh) = p*65536 + kh*16384 (256 rows x 64B)
//                                            B(p,kh) = p*65536 + 32768 + kh*16384
// Swizzle: phys 16B-chunk = logical ^ ((row>>1)&3); stage pre-swizzles the global source,
// gload_lds dest linear; asm ds_read XORs the chunk. gload_lds imm offset = 0 always.
#define GLD(PTR, LOFF)                                                           \
  __builtin_amdgcn_global_load_lds(                                              \
      (const __attribute__((address_space(1))) void*)(PTR),                      \
      (__attribute__((address_space(3))) void*)(lds + (LOFF) + wslot), 16, 0, 0)

#define STG2(LP, KH_, PA, PB)                                                    \
  do {                                                                           \
    GLD((PA), (LP) + (KH_) * 8192);                                              \
    GLD((PA) + 128 * KDIM, (LP) + (KH_) * 8192 + 4096);                          \
    GLD((PB), (LP) + 16384 + (KH_) * 8192);                                      \
    GLD((PB) + 128 * KDIM, (LP) + 16384 + (KH_) * 8192 + 4096);                  \
  } while (0)

#define VM4 asm volatile("s_waitcnt vmcnt(4)" ::: "memory")
#define SB0 __builtin_amdgcn_sched_barrier(0)
// Counted lgkm waits: N = ds_reads issued THIS window; FIFO retire => last window's
// reads (the banks the MFMA consumes) are complete while this window's stay in flight.
#define LGKM4 asm volatile("s_waitcnt lgkmcnt(4)" ::: "memory")
#define LGKM8 asm volatile("s_waitcnt lgkmcnt(8)" ::: "memory")

// Inline-asm ds_read_b128: compiler does NOT track these in lgkmcnt -> our counted
// waits are the only gate (+ SB0 so MFMAs can't hoist above the wait; rule #18).
#define DSR(DST, ABASE, OFF)                                                     \
  asm volatile("ds_read_b128 %0, %1 offset:%2"                                   \
               : "=&v"(DST) : "v"(ABASE), "i"(OFF))

#define RD_AV(BANK, AB, KH, H)                                                   \
  do {                                                                           \
    DSR(BANK[0], AB, (KH) * 16384 + ((H) * 4 + 0) * 1024);                       \
    DSR(BANK[1], AB, (KH) * 16384 + ((H) * 4 + 1) * 1024);                       \
    DSR(BANK[2], AB, (KH) * 16384 + ((H) * 4 + 2) * 1024);                       \
    DSR(BANK[3], AB, (KH) * 16384 + ((H) * 4 + 3) * 1024);                       \
  } while (0)
#define RD_BV(BANK, BB, KH)                                                      \
  do {                                                                           \
    DSR(BANK[0], BB, (KH) * 16384 + 0 * 1024);                                   \
    DSR(BANK[1], BB, (KH) * 16384 + 1 * 1024);                                   \
    DSR(BANK[2], BB, (KH) * 16384 + 2 * 1024);                                   \
    DSR(BANK[3], BB, (KH) * 16384 + 3 * 1024);                                   \
  } while (0)

// MFMA cluster on banks read LAST window; gated by counted lgkm + sched fence.
#define MM(BA, BB, MIH_, LG)                                                     \
  do {                                                                           \
    LG; SB0;                                                                     \
    __builtin_amdgcn_s_setprio(1);                                               \
    _Pragma("unroll") for (int i = 0; i < 4; ++i)                                \
      _Pragma("unroll") for (int ni = 0; ni < 4; ++ni)                           \
        acc[(MIH_) * 4 + i][ni] = __builtin_amdgcn_mfma_f32_16x16x32_bf16(       \
            BA[i], BB[ni], acc[(MIH_) * 4 + i][ni], 0, 0, 0);                    \
    __builtin_amdgcn_s_setprio(0);                                               \
    __builtin_amdgcn_s_barrier();                                                \
  } while (0)

#define ADV do { a0 += 64; b0 += 64; } while (0)

__global__ __launch_bounds__(512, 2) void k_lstm_gemm(
    const __hip_bfloat16* __restrict__ xh, const __hip_bfloat16* __restrict__ wt,
    const float* __restrict__ cin,
    const float* __restrict__ bfp, const float* __restrict__ bip,
    const float* __restrict__ bcp, const float* __restrict__ bop,
    float* __restrict__ out) {
  __shared__ __hip_bfloat16 lds[65536];   // 128 KiB
  const int tid  = threadIdx.x;
  const int lane = tid & 63;
  const int wid  = tid >> 6;
  const int wm = wid >> 2, wn = wid & 3;   // 2 x 4 waves; wave output = 128 x 64
  const int wmb = wm << 7, wnb = wn << 6;

  // T1: XCD-chunked bijective swizzle (256 blocks = 8 XCD x 32)
  const int bid  = blockIdx.x;
  const int flat = ((bid & 7) << 5) | (bid >> 3);
  const int m0 = (flat & 15) << 8;
  const int n0 = (flat >> 4) << 8;         // interleaved-gate column space

  f32x4 acc[8][4] = {};                    // [mi][gate] (AGPR)

  // ---- staging addressing: each GLD covers 128 rows x 4 chunks(16B) ----
  const int wslot = wid << 9;
  const int cl = (((lane & 3) ^ ((lane >> 3) & 3)) << 3);
  const __hip_bfloat16* a0 = xh + (int64_t)(m0 + (tid >> 2)) * KDIM + cl;
  const __hip_bfloat16* b0 = wt + (int64_t)(n0 + (tid >> 2)) * KDIM + cl;

  // ---- fragment read base addresses (bytes, lane-constant; one per parity/matrix) ----
  const int frow = lane & 15;
  const int rx   = (((lane >> 4) ^ ((frow >> 1) & 3)) << 3);  // swizzled chunk (elems)
  const int aA0 = ((((wmb + frow) << 5) + rx) << 1);          // A parity 0 byte base
  const int aA1 = aA0 + 65536;
  const int bB0 = (((16384 + ((wnb + frow) << 5) + rx)) << 1);// B parity 0 byte base
  const int bB1 = bB0 + 65536;

  bf16x8 avA[4], avB[4], bvA[4], bvB[4];   // fully-banked read-ahead

  // ---- prologue: stage tile0 (parity 0), land AB(0,0), pre-read window-0 banks ----
  STG2(0, 0, a0, b0);                      // AB(0,0)
  STG2(0, 1, a0 + 32, b0 + 32);            // AB(0,1)
  ADV;                                     // pointers -> tile 1
  VM4;                                     // AB(0,0) landed
  __builtin_amdgcn_s_barrier();
  RD_AV(avA, aA0, 0, 0);
  RD_BV(bvA, bB0, 0);

  for (int t = 0; t < NT; t += 2) {
    {  // tile t (parity 0): stage tile t+1 -> parity 1
      // w0: MFMA(avA,bvA) | read avB<-A(0,kh0)h1 | stage AB(1,kh0) | vmcnt
      RD_AV(avB, aA0, 0, 1);
      STG2(32768, 0, a0, b0);
      VM4; MM(avA, bvA, 0, LGKM4);
      // w1: MFMA(avB,bvA) | read avA<-A(0,kh1)h0, bvB<-B(0,kh1) | stage AB(1,kh1)
      RD_AV(avA, aA0, 1, 0); RD_BV(bvB, bB0, 1);
      STG2(32768, 1, a0 + 32, b0 + 32);
      MM(avB, bvA, 1, LGKM8);
      // w2: MFMA(avA,bvB) | read avB<-A(0,kh1)h1 | vmcnt
      RD_AV(avB, aA0, 1, 1);
      VM4; MM(avA, bvB, 0, LGKM4);
      // w3: MFMA(avB,bvB) | read avA<-A(1,kh0)h0, bvA<-B(1,kh0)
      RD_AV(avA, aA1, 0, 0); RD_BV(bvA, bB1, 0);
      MM(avB, bvB, 1, LGKM8);
    }
    if (t != 30) ADV;
    {  // tile t+1 (parity 1): stage tile t+2 -> parity 0 (t=30: dead re-stage, in-bounds)
      RD_AV(avB, aA1, 0, 1);
      STG2(0, 0, a0, b0);
      VM4; MM(avA, bvA, 0, LGKM4);
      RD_AV(avA, aA1, 1, 0); RD_BV(bvB, bB1, 1);
      STG2(0, 1, a0 + 32, b0 + 32);
      MM(avB, bvA, 1, LGKM8);
      RD_AV(avB, aA1, 1, 1);
      VM4; MM(avA, bvB, 0, LGKM4);
      RD_AV(avA, aA0, 0, 0); RD_BV(bvA, bB0, 0);  // next-tile kh0 (dead on final iter)
      MM(avB, bvB, 1, LGKM8);
    }
    ADV;
  }
  asm volatile("s_waitcnt lgkmcnt(0)" ::: "memory");  // drain dead tail reads

  // ---- fused LSTM epilogue (fp32 outputs: h_new, h_new, c_new) ----
  const int j = (((n0 >> 6) + wn) << 4) + frow;     // h-column in [0,1024)
  const float vbf = bfp[j], vbi = bip[j], vbc = bcp[j], vbo = bop[j];
  const int q4 = (lane >> 4) << 2;
  float* outh1 = out;
  float* outh2 = out + (int64_t)BROWS * DH;
  float* outc  = out + (int64_t)2 * BROWS * DH;
#pragma unroll
  for (int mi = 0; mi < 8; ++mi) {
    const int mbase = m0 + wmb + (mi << 4) + q4;
#pragma unroll
    for (int r = 0; r < 4; ++r) {
      const int m = mbase + r;
      const int64_t idx = (int64_t)m * DH + j;
      float fg = sig_(acc[mi][0][r] + vbf);
      float ig = sig_(acc[mi][1][r] + vbi);
      float cg = tanh_(acc[mi][2][r] + vbc);
      float og = sig_(acc[mi][3][r] + vbo);
      float cn = fg * cin[idx] + ig * cg;
      float hn = og * tanh_(cn);
      outh1[idx] = hn;
      outh2[idx] = hn;
      outc[idx]  = cn;
    }
  }
}

extern "C" void kernel_launch(void* const* d_in, const int* in_sizes, int n_in,
                              void* d_out, int out_size, void* d_ws, size_t ws_size,
                              hipStream_t stream) {
  const float* x  = (const float*)d_in[0];
  const float* h  = (const float*)d_in[1];
  const float* c  = (const float*)d_in[2];
  const float* Wf = (const float*)d_in[3];
  const float* bf = (const float*)d_in[4];
  const float* Wi = (const float*)d_in[5];
  const float* bi = (const float*)d_in[6];
  const float* Wc = (const float*)d_in[7];
  const float* bc = (const float*)d_in[8];
  const float* Wo = (const float*)d_in[9];
  const float* bo = (const float*)d_in[10];
  float* out = (float*)d_out;

  __hip_bfloat16* xh = (__hip_bfloat16*)d_ws;                    // 4096x2048 bf16 (16 MiB)
  __hip_bfloat16* wt = xh + (int64_t)BROWS * KDIM;               // 4096x2048 bf16 (16 MiB)

  hipLaunchKernelGGL(k_prep, dim3(6144), dim3(256), 0, stream,
                     x, h, Wf, Wi, Wc, Wo, xh, wt);
  hipLaunchKernelGGL(k_lstm_gemm, dim3(256), dim3(512), 0, stream,
                     xh, wt, c, bf, bi, bc, bo, out);
}

// Round 13
// 86.701 us; speedup vs baseline: 1.1368x; 1.0124x over previous
//
#include <hip/hip_runtime.h>
#include <hip/hip_bf16.h>
#include <cstdint>

typedef __bf16 bf16x8 __attribute__((ext_vector_type(8)));
typedef float f32x4 __attribute__((ext_vector_type(4)));

#define BROWS 4096
#define DH    1024
#define KDIM  2048   // D_IN + D_H
#define NT    32     // K-tiles of 64

// ---------------- fused prep: concat(x,h)->bf16 xh  +  W transpose/interleave->wt ----------------
__global__ __launch_bounds__(256) void k_prep(const float* __restrict__ x,
                                              const float* __restrict__ h,
                                              const float* __restrict__ Wf,
                                              const float* __restrict__ Wi,
                                              const float* __restrict__ Wc,
                                              const float* __restrict__ Wo,
                                              __hip_bfloat16* __restrict__ xh,
                                              __hip_bfloat16* __restrict__ wt) {
  __shared__ float t[64][65];
  const int tid = threadIdx.x;
  if (blockIdx.x < 4096) {
    // concat(x,h) -> bf16 xh[4096][2048], 8 elems/thread
    int64_t idx = ((int64_t)blockIdx.x * 256 + tid) * 8;
    int row = (int)(idx >> 11);
    int col = (int)(idx & 2047);
    const float* src = (col < 1024) ? (x + (int64_t)row * 1024 + col)
                                    : (h + (int64_t)row * 1024 + (col - 1024));
    float4 v0 = reinterpret_cast<const float4*>(src)[0];
    float4 v1 = reinterpret_cast<const float4*>(src)[1];
    alignas(16) __hip_bfloat16 o8[8];
    o8[0] = __float2bfloat16(v0.x); o8[1] = __float2bfloat16(v0.y);
    o8[2] = __float2bfloat16(v0.z); o8[3] = __float2bfloat16(v0.w);
    o8[4] = __float2bfloat16(v1.x); o8[5] = __float2bfloat16(v1.y);
    o8[6] = __float2bfloat16(v1.z); o8[7] = __float2bfloat16(v1.w);
    *reinterpret_cast<int4*>(xh + idx) = *reinterpret_cast<const int4*>(o8);
  } else {
    // W_g[k][j] fp32 -> wt[n'][k] bf16, n' = (j>>4)*64 + g*16 + (j&15)
    const int b = blockIdx.x - 4096;   // 2048 = 4 gates * 16 jt * 32 kt
    const int g  = b & 3;
    const int jt = (b >> 2) & 15;
    const int kt = b >> 6;
    const float* W = (g == 0) ? Wf : (g == 1) ? Wi : (g == 2) ? Wc : Wo;
    const int j0 = jt << 6, k0 = kt << 6;
#pragma unroll
    for (int i = 0; i < 4; ++i) {
      int r = (tid >> 4) + (i << 4);
      int c = (tid & 15) << 2;
      float4 v = *reinterpret_cast<const float4*>(W + (int64_t)(k0 + r) * 1024 + j0 + c);
      t[r][c + 0] = v.x; t[r][c + 1] = v.y; t[r][c + 2] = v.z; t[r][c + 3] = v.w;
    }
    __syncthreads();
#pragma unroll
    for (int i = 0; i < 2; ++i) {
      int task = tid + (i << 8);
      int rr = task >> 3;
      int kc = (task & 7) << 3;
      int np = (((jt << 2) + (rr >> 4)) << 6) + (g << 4) + (rr & 15);
      alignas(16) __hip_bfloat16 o8[8];
#pragma unroll
      for (int e = 0; e < 8; ++e) o8[e] = __float2bfloat16(t[kc + e][rr]);
      *reinterpret_cast<int4*>(wt + (int64_t)np * KDIM + k0 + kc) =
          *reinterpret_cast<const int4*>(o8);
    }
  }
}

// ---------------- fused GEMM + LSTM epilogue: 256x256, m201-template phases ----------------
__device__ __forceinline__ float sig_(float v) {
  return __builtin_amdgcn_rcpf(1.0f + __expf(-v));
}
__device__ __forceinline__ float tanh_(float v) {
  return fmaf(2.0f, __builtin_amdgcn_rcpf(1.0f + __expf(-2.0f * v)), -1.0f);
}

// LDS regions (elements): parity p, k-half kh:  A(p,kh) = p*32768 + kh*8192 (256 rows x 32)
//                                               B(p,kh) = p*32768 + 16384 + kh*8192
// Swizzle: phys 16B-chunk = logical ^ ((row>>1)&3); stage pre-swizzles the global source,
// gload_lds dest linear; reads XOR the chunk. gload_lds imm offset = 0 always.
#define GLD(PTR, LOFF)                                                           \
  __builtin_amdgcn_global_load_lds(                                              \
      (const __attribute__((address_space(1))) void*)(PTR),                      \
      (__attribute__((address_space(3))) void*)(lds + (LOFF) + wslot), 16, 0, 0)

// stage one unit (128+128 rows x 32 cols of one matrix, one kh): 2 GLDs
#define STGA(PTR, LOFF)                                                          \
  do { GLD((PTR), (LOFF)); GLD((PTR) + 128 * KDIM, (LOFF) + 4096); } while (0)

#define LDSA(P, KH, MI)                                                          \
  (*reinterpret_cast<const bf16x8*>(lds + (P) * 32768 + (KH) * 8192 + abase + (MI) * 512))
#define LDSB(P, KH, NI)                                                          \
  (*reinterpret_cast<const bf16x8*>(lds + (P) * 32768 + (KH) * 8192 + bbase + (NI) * 512))

#define VM4  asm volatile("s_waitcnt vmcnt(4)" ::: "memory")
#define NOVM do {} while (0)

#define RD_A(P_, KH_, H_)                                                        \
  _Pragma("unroll") for (int i = 0; i < 4; ++i) av[i] = LDSA(P_, KH_, (H_) * 4 + i)
#define RD_B(P_, KH_)                                                            \
  _Pragma("unroll") for (int ni = 0; ni < 4; ++ni) bv[ni] = LDSB(P_, KH_, ni)

// m201 phase: {reads | 1 stage unit | optional counted vmcnt} -> bar -> lgkm0 -> MFMA -> bar
#define PH(P, KH, H, RDB, STG_STMT, VM_STMT)                                     \
  do {                                                                           \
    if (RDB) { RD_B(P, KH); }                                                    \
    RD_A(P, KH, H);                                                              \
    STG_STMT;                                                                    \
    VM_STMT;                                                                     \
    __builtin_amdgcn_s_barrier();                                                \
    asm volatile("s_waitcnt lgkmcnt(0)" ::: "memory");                           \
    __builtin_amdgcn_sched_barrier(0);                                           \
    __builtin_amdgcn_s_setprio(1);                                               \
    _Pragma("unroll") for (int i = 0; i < 4; ++i)                                \
      _Pragma("unroll") for (int ni = 0; ni < 4; ++ni)                           \
        acc[(H) * 4 + i][ni] = __builtin_amdgcn_mfma_f32_16x16x32_bf16(          \
            av[i], bv[ni], acc[(H) * 4 + i][ni], 0, 0, 0);                       \
    __builtin_amdgcn_s_setprio(0);                                               \
    __builtin_amdgcn_s_barrier();                                                \
  } while (0)

// one K-tile, read parity P, stage into SLP = (P^1)*32768 (sources already at next tile)
#define TILE(P, SLP)                                                             \
  do {                                                                           \
    PH(P, 0, 0, 1, STGA(a0,      (SLP)),                 NOVM);                  \
    PH(P, 0, 1, 0, STGA(b0,      (SLP) + 16384),         VM4);                   \
    PH(P, 1, 0, 1, STGA(a0 + 32, (SLP) + 8192),          NOVM);                  \
    PH(P, 1, 1, 0, STGA(b0 + 32, (SLP) + 16384 + 8192),  VM4);                   \
  } while (0)

#define ADV do { a0 += 64; b0 += 64; } while (0)

__global__ __launch_bounds__(512, 2) void k_lstm_gemm(
    const __hip_bfloat16* __restrict__ xh, const __hip_bfloat16* __restrict__ wt,
    const float* __restrict__ cin,
    const float* __restrict__ bfp, const float* __restrict__ bip,
    const float* __restrict__ bcp, const float* __restrict__ bop,
    float* __restrict__ out) {
  __shared__ __hip_bfloat16 lds[65536];   // 128 KiB
  const int tid  = threadIdx.x;
  const int lane = tid & 63;
  const int wid  = tid >> 6;
  const int wm = wid >> 2, wn = wid & 3;   // 2 x 4 waves; wave output = 128 x 64
  const int wmb = wm << 7, wnb = wn << 6;

  // T1: XCD-chunked bijective swizzle (256 blocks = 8 XCD x 32)
  const int bid  = blockIdx.x;
  const int flat = ((bid & 7) << 5) | (bid >> 3);
  const int m0 = (flat & 15) << 8;
  const int n0 = (flat >> 4) << 8;         // interleaved-gate column space

  f32x4 acc[8][4] = {};                    // [mi][gate] (AGPR)

  // ---- staging addressing: each GLD covers 128 rows x 4 chunks(16B) ----
  const int wslot = wid << 9;
  const int cl = (((lane & 3) ^ ((lane >> 3) & 3)) << 3);
  const __hip_bfloat16* a0 = xh + (int64_t)(m0 + (tid >> 2)) * KDIM + cl;
  const __hip_bfloat16* b0 = wt + (int64_t)(n0 + (tid >> 2)) * KDIM + cl;

  // ---- fragment read bases (lane-constant) ----
  const int frow = lane & 15;
  const int rx   = (((lane >> 4) ^ ((frow >> 1) & 3)) << 3);  // swizzled chunk (elems)
  const int abase = ((wmb + frow) << 5) + rx;
  const int bbase = 16384 + ((wnb + frow) << 5) + rx;

  bf16x8 av[4], bv[4];

  // ---- prologue: stage tile0's 4 units into parity 0; drain kh0 units; barrier ----
  STGA(a0, 0);                       // t0 A(kh0)
  STGA(b0, 16384);                   // t0 B(kh0)
  STGA(a0 + 32, 8192);               // t0 A(kh1)
  STGA(b0 + 32, 16384 + 8192);       // t0 B(kh1)
  ADV;                               // pointers -> tile 1
  VM4;                               // kh0 units landed
  __builtin_amdgcn_s_barrier();

  for (int t = 0; t < NT; t += 2) {
    TILE(0, 32768);                  // tile t   (parity 0), stage tile t+1 -> parity 1
    if (t != 30) ADV;
    TILE(1, 0);                      // tile t+1 (parity 1), stage tile t+2 -> parity 0
    ADV;                             // (t=30: dead re-stage of tile 31, in-bounds)
  }

  // ---- fused LSTM epilogue (fp32 outputs: h_new, h_new, c_new) ----
  const int j = (((n0 >> 6) + wn) << 4) + frow;     // h-column in [0,1024)
  const float vbf = bfp[j], vbi = bip[j], vbc = bcp[j], vbo = bop[j];
  const int q4 = (lane >> 4) << 2;
  float* outh1 = out;
  float* outh2 = out + (int64_t)BROWS * DH;
  float* outc  = out + (int64_t)2 * BROWS * DH;
#pragma unroll
  for (int mi = 0; mi < 8; ++mi) {
    const int mbase = m0 + wmb + (mi << 4) + q4;
#pragma unroll
    for (int r = 0; r < 4; ++r) {
      const int m = mbase + r;
      const int64_t idx = (int64_t)m * DH + j;
      float fg = sig_(acc[mi][0][r] + vbf);
      float ig = sig_(acc[mi][1][r] + vbi);
      float cg = tanh_(acc[mi][2][r] + vbc);
      float og = sig_(acc[mi][3][r] + vbo);
      float cn = fg * cin[idx] + ig * cg;
      float hn = og * tanh_(cn);
      outh1[idx] = hn;
      outh2[idx] = hn;
      outc[idx]  = cn;
    }
  }
}

extern "C" void kernel_launch(void* const* d_in, const int* in_sizes, int n_in,
                              void* d_out, int out_size, void* d_ws, size_t ws_size,
                              hipStream_t stream) {
  const float* x  = (const float*)d_in[0];
  const float* h  = (const float*)d_in[1];
  const float* c  = (const float*)d_in[2];
  const float* Wf = (const float*)d_in[3];
  const float* bf = (const float*)d_in[4];
  const float* Wi = (const float*)d_in[5];
  const float* bi = (const float*)d_in[6];
  const float* Wc = (const float*)d_in[7];
  const float* bc = (const float*)d_in[8];
  const float* Wo = (const float*)d_in[9];
  const float* bo = (const float*)d_in[10];
  float* out = (float*)d_out;

  __hip_bfloat16* xh = (__hip_bfloat16*)d_ws;                    // 4096x2048 bf16 (16 MiB)
  __hip_bfloat16* wt = xh + (int64_t)BROWS * KDIM;               // 4096x2048 bf16 (16 MiB)

  hipLaunchKernelGGL(k_prep, dim3(6144), dim3(256), 0, stream,
                     x, h, Wf, Wi, Wc, Wo, xh, wt);
  hipLaunchKernelGGL(k_lstm_gemm, dim3(256), dim3(512), 0, stream,
                     xh, wt, c, bf, bi, bc, bo, out);
}